// Round 2
// baseline (413.175 us; speedup 1.0000x reference)
//
#include <hip/hip_runtime.h>
#include <math.h>

#define B_ 16
#define L_ 512
#define D_ 768
#define H_ 12
#define K_ 128
#define U_ 256
#define NH_ 4
#define HD_ 64
#define OUTROWS_ 130   // 1 class + 128 preserved + 1 new
#define IMPCH_ 64      // importance chunks per b (96 rows each)

// ---------------------------------------------------------------------------
// K1: fused front. Blocks [0, 1024): importance partials (b = bx>>6,
// chunk = bx&63, 96 rows each, LDS-reduced 6->1). Blocks [1024, 1280):
// sentence partials (lean 3-sync softmax + float4 accumulation).
// ---------------------------------------------------------------------------
__global__ __launch_bounds__(768) void front_kernel(
    const float* __restrict__ sas, const float* __restrict__ hidden,
    const float* __restrict__ mask, float* __restrict__ part,
    float* __restrict__ sent_part) {
  const int t = threadIdx.x;
  if (blockIdx.x < B_ * IMPCH_) {
    __shared__ float4 lbuf[6][128];
    const int b = blockIdx.x >> 6, chunk = blockIdx.x & 63;
    const int col4 = t & 127;      // float4 column 0..127 (512 floats)
    const int rg = t >> 7;         // row group 0..5
    const float4* base = (const float4*)sas +
        ((size_t)(b * (H_ * L_) + chunk * 96 + rg * 16)) * 128 + col4;
    float4 a = make_float4(0.f, 0.f, 0.f, 0.f);
    #pragma unroll
    for (int k = 0; k < 16; ++k) {
      float4 v = base[(size_t)k * 128];
      a.x += v.x; a.y += v.y; a.z += v.z; a.w += v.w;
    }
    lbuf[rg][col4] = a;
    __syncthreads();
    if (rg == 0) {
      float4 o = lbuf[0][col4];
      #pragma unroll
      for (int g = 1; g < 6; ++g) {
        float4 v = lbuf[g][col4];
        o.x += v.x; o.y += v.y; o.z += v.z; o.w += v.w;
      }
      const float s = 1.0f / 12.0f;
      o.x *= s; o.y *= s; o.z *= s; o.w *= s;
      ((float4*)part)[((size_t)b * IMPCH_ + chunk) * 128 + col4] = o;
    }
  } else {
    __shared__ float att[L_];
    __shared__ float red_m[12], red_s[12];
    __shared__ float4 cbuf[4][192];
    const int i = blockIdx.x - B_ * IMPCH_;
    const int b = i >> 4, chunk = i & 15;
    const int wave = t >> 6, lane = t & 63;
    const float m = (t < L_) ? mask[b * L_ + t] : -INFINITY;
    float r = m;
    #pragma unroll
    for (int off = 32; off > 0; off >>= 1) r = fmaxf(r, __shfl_down(r, off, 64));
    if (lane == 0) red_m[wave] = r;
    __syncthreads();
    float mx = red_m[0];
    #pragma unroll
    for (int w = 1; w < 12; ++w) mx = fmaxf(mx, red_m[w]);
    const float e = (t < L_) ? expf(m - mx) : 0.f;
    float rs = e;
    #pragma unroll
    for (int off = 32; off > 0; off >>= 1) rs += __shfl_down(rs, off, 64);
    if (lane == 0) red_s[wave] = rs;
    __syncthreads();
    float se = 0.f;
    #pragma unroll
    for (int w = 0; w < 12; ++w) se += red_s[w];
    if (t < L_) att[t] = e / se;
    __syncthreads();
    // float4 accumulation: 192 cols x 4 l-subgroups of 8
    const int c4 = t % 192, sub = t / 192;
    const int l0 = chunk * 32 + sub * 8;
    const float4* h4 = (const float4*)hidden + ((size_t)b * L_ + l0) * 192 + c4;
    float4 acc = make_float4(0.f, 0.f, 0.f, 0.f);
    #pragma unroll
    for (int ii = 0; ii < 8; ++ii) {
      const float w = att[l0 + ii];
      const float4 hv = h4[(size_t)ii * 192];
      acc.x += w * hv.x; acc.y += w * hv.y; acc.z += w * hv.z; acc.w += w * hv.w;
    }
    cbuf[sub][c4] = acc;
    __syncthreads();
    if (t < 192) {
      float4 o = cbuf[0][t];
      #pragma unroll
      for (int g = 1; g < 4; ++g) {
        const float4 v = cbuf[g][t];
        o.x += v.x; o.y += v.y; o.z += v.z; o.w += v.w;
      }
      ((float4*)sent_part)[((size_t)b * 16 + chunk) * 192 + t] = o;
    }
  }
}

// ---------------------------------------------------------------------------
// K2: blocks 0..63 = qproj per (b,h); blocks 64..79 = topk + gather + zero outv.
// ---------------------------------------------------------------------------
__global__ __launch_bounds__(768) void qproj_topk_kernel(
    const float* __restrict__ sent_part, const float* __restrict__ Wq,
    const float* __restrict__ Wk, float* __restrict__ wqe,
    const float* __restrict__ part, const float* __restrict__ mask,
    const float* __restrict__ hidden, float* __restrict__ out0,
    float* __restrict__ out1, float* __restrict__ outv) {
  __shared__ float s[D_];
  __shared__ float qvh[HD_];
  __shared__ float v[L_];
  __shared__ int lidx[K_];
  __shared__ int wcnt[12];
  const int t = threadIdx.x;
  const int wave = t >> 6, lane = t & 63;

  if (blockIdx.x < 64) {
    const int b = blockIdx.x >> 2, h = blockIdx.x & 3;
    {
      const float* sp = sent_part + (size_t)b * 16 * D_ + t;
      float a = 0.f;
      #pragma unroll
      for (int c = 0; c < 16; ++c) a += sp[(size_t)c * D_];
      s[t] = a;
    }
    __syncthreads();
    for (int u = wave; u < HD_; u += 12) {
      const float* wr = Wq + (size_t)(h * HD_ + u) * D_;
      float acc = 0.f;
      #pragma unroll
      for (int k = 0; k < 12; ++k) {
        const int d = lane + (k << 6);
        acc += wr[d] * s[d];
      }
      #pragma unroll
      for (int o = 32; o > 0; o >>= 1) acc += __shfl_down(acc, o, 64);
      if (lane == 0) qvh[u] = acc;
    }
    __syncthreads();
    {
      float acc = 0.f;
      const float* wk = Wk + (size_t)(h * HD_) * D_ + t;
      #pragma unroll 4
      for (int j = 0; j < HD_; ++j) acc += qvh[j] * wk[(size_t)j * D_];
      wqe[((size_t)b * NH_ + h) * D_ + t] = acc;
    }
  } else {
    const int b = blockIdx.x - 64;
    if (t < U_) outv[b * U_ + t] = 0.f;  // zero accumulator for K4 atomics
    if (t < L_) {
      const float* pp = part + (size_t)b * IMPCH_ * L_ + t;
      float sum = 0.f;
      #pragma unroll 8
      for (int g = 0; g < IMPCH_; ++g) sum += pp[(size_t)g * L_];
      v[t] = sum;
    }
    __syncthreads();
    bool sel = false;
    if (t < L_) {
      const float mv = v[t];
      int cnt = 0;
      #pragma unroll 8
      for (int j = 0; j < L_; ++j) {
        float o = v[j];
        cnt += (o > mv) || (o == mv && j < t);  // stable tie-break
      }
      sel = cnt < K_;
    }
    const unsigned long long ball = __ballot(sel);
    if (lane == 0) wcnt[wave] = __popcll(ball);
    __syncthreads();
    int base = 0;
    for (int w = 0; w < wave; ++w) base += wcnt[w];
    const int pos = base + __popcll(ball & ((1ull << lane) - 1ull));
    if (sel) {
      lidx[pos] = t;
      out1[b * OUTROWS_ + 1 + pos] = mask[b * L_ + t];
    }
    if (t == 0) {
      out1[b * OUTROWS_ + 0] = 0.f;
      out1[b * OUTROWS_ + OUTROWS_ - 1] = 0.f;
    }
    __syncthreads();
    const float4* hb4 = (const float4*)(hidden + (size_t)b * L_ * D_);
    float4* ob4 = (float4*)(out0 + (size_t)b * OUTROWS_ * D_);
    const int NG = (K_ + 1) * 192;  // 129 rows * 192 float4
    for (int i = t; i < NG; i += 768) {
      const int r = i / 192;
      const int c = i - r * 192;
      const int src = (r == 0) ? 0 : lidx[r - 1];
      ob4[r * 192 + c] = hb4[src * 192 + c];
    }
  }
}

// ---------------------------------------------------------------------------
// K3: scores[b,h,l] = (hidden[b,l,:] . wq_eff[b,h,:]) / sqrt(D), masked.
// ---------------------------------------------------------------------------
__global__ __launch_bounds__(256) void score_kernel(
    const float* __restrict__ hidden, const float* __restrict__ mask,
    const float* __restrict__ wqe, float* __restrict__ scores) {
  __shared__ float4 wq4[NH_ * 192];
  const int b = blockIdx.x, chunk = blockIdx.y, t = threadIdx.x;
  {
    const float4* wsrc = (const float4*)(wqe + (size_t)b * NH_ * D_);
    for (int i = t; i < NH_ * 192; i += 256) wq4[i] = wsrc[i];
  }
  __syncthreads();
  const int wave = t >> 6, lane = t & 63;
  const float scale = 0.03608439182435161f;  // 1/sqrt(768)
  #pragma unroll
  for (int r = 0; r < 8; ++r) {
    const int l = chunk * 32 + wave * 8 + r;
    const float4* hr4 = (const float4*)(hidden + ((size_t)b * L_ + l) * D_);
    float s0 = 0.f, s1 = 0.f, s2 = 0.f, s3 = 0.f;
    #pragma unroll
    for (int jj = 0; jj < 3; ++jj) {
      const int c = lane + 64 * jj;
      const float4 hv = hr4[c];
      const float4 w0 = wq4[0 * 192 + c];
      const float4 w1 = wq4[1 * 192 + c];
      const float4 w2 = wq4[2 * 192 + c];
      const float4 w3 = wq4[3 * 192 + c];
      s0 += hv.x * w0.x + hv.y * w0.y + hv.z * w0.z + hv.w * w0.w;
      s1 += hv.x * w1.x + hv.y * w1.y + hv.z * w1.z + hv.w * w1.w;
      s2 += hv.x * w2.x + hv.y * w2.y + hv.z * w2.z + hv.w * w2.w;
      s3 += hv.x * w3.x + hv.y * w3.y + hv.z * w3.z + hv.w * w3.w;
    }
    #pragma unroll
    for (int o = 32; o > 0; o >>= 1) {
      s0 += __shfl_down(s0, o, 64);
      s1 += __shfl_down(s1, o, 64);
      s2 += __shfl_down(s2, o, 64);
      s3 += __shfl_down(s3, o, 64);
    }
    if (lane == 0) {
      const bool kp = mask[b * L_ + l] < -10.f;
      float* sp = scores + (size_t)b * NH_ * L_ + l;
      sp[0 * L_] = kp ? -INFINITY : s0 * scale;
      sp[1 * L_] = kp ? -INFINITY : s1 * scale;
      sp[2 * L_] = kp ? -INFINITY : s2 * scale;
      sp[3 * L_] = kp ? -INFINITY : s3 * scale;
    }
  }
}

// ---------------------------------------------------------------------------
// K4: fused softmax (lean, 3 syncs) + ctx accumulate (float4, 192 cols x 4
// heads) + partial ctx.Wv dots -> atomicAdd into outv. Grid (B,16), 768 thr.
// Replaces ctx_prob + outv kernels; deletes the 25 MB ctx_part roundtrip.
// ---------------------------------------------------------------------------
__global__ __launch_bounds__(768) void ctx_outv_kernel(
    const float* __restrict__ hidden, const float* __restrict__ scores,
    const float* __restrict__ Wv, float* __restrict__ outv) {
  __shared__ float pr[NH_][32];
  __shared__ float red_m[NH_][12], red_s[NH_][12];
  __shared__ __align__(16) float ctxs[NH_ * D_];
  const int b = blockIdx.x, chunk = blockIdx.y, t = threadIdx.x;
  const int wave = t >> 6, lane = t & 63;
  const int l0 = chunk * 32;

  float val[NH_];
  #pragma unroll
  for (int h = 0; h < NH_; ++h)
    val[h] = (t < L_) ? scores[((size_t)b * NH_ + h) * L_ + t] : -INFINITY;
  #pragma unroll
  for (int h = 0; h < NH_; ++h) {
    float r = val[h];
    #pragma unroll
    for (int off = 32; off > 0; off >>= 1) r = fmaxf(r, __shfl_down(r, off, 64));
    if (lane == 0) red_m[h][wave] = r;
  }
  __syncthreads();
  float e[NH_];
  #pragma unroll
  for (int h = 0; h < NH_; ++h) {
    float mx = red_m[h][0];
    #pragma unroll
    for (int w = 1; w < 12; ++w) mx = fmaxf(mx, red_m[h][w]);
    e[h] = (t < L_) ? expf(val[h] - mx) : 0.f;
    float rs = e[h];
    #pragma unroll
    for (int off = 32; off > 0; off >>= 1) rs += __shfl_down(rs, off, 64);
    if (lane == 0) red_s[h][wave] = rs;
  }
  __syncthreads();
  if (t >= l0 && t < l0 + 32) {
    #pragma unroll
    for (int h = 0; h < NH_; ++h) {
      float se = 0.f;
      #pragma unroll
      for (int w = 0; w < 12; ++w) se += red_s[h][w];
      pr[h][t - l0] = e[h] / se;
    }
  }
  __syncthreads();

  // ctx accumulate: thread = (col4 0..191, head 0..3); rows reused via L1.
  const int c4 = t % 192, hh = t / 192;
  const float4* h4 = (const float4*)hidden + ((size_t)b * L_ + l0) * 192 + c4;
  float4 acc = make_float4(0.f, 0.f, 0.f, 0.f);
  #pragma unroll 8
  for (int l = 0; l < 32; ++l) {
    const float w = pr[hh][l];
    const float4 hv = h4[(size_t)l * 192];
    acc.x += w * hv.x; acc.y += w * hv.y; acc.z += w * hv.z; acc.w += w * hv.w;
  }
  ((float4*)ctxs)[hh * 192 + c4] = acc;
  __syncthreads();

  // outv[b,hu] += ctx_chunk[hu>>6,:] . Wv[hu,:]
  for (int hu = wave; hu < U_; hu += 12) {
    const float* wr = Wv + (size_t)hu * D_;
    const float* ch = ctxs + (hu >> 6) * D_;
    float a = 0.f;
    #pragma unroll
    for (int k = 0; k < 12; ++k) {
      const int d = lane + (k << 6);
      a += wr[d] * ch[d];
    }
    #pragma unroll
    for (int off = 32; off > 0; off >>= 1) a += __shfl_down(a, off, 64);
    if (lane == 0) atomicAdd(&outv[b * U_ + hu], a);
  }
}

// ---------------------------------------------------------------------------
// K5: new_token[b,d] = bo[d] + outv[b,:] . Wo[d,:]. Grid (B,4), 192 thr.
// ---------------------------------------------------------------------------
__global__ __launch_bounds__(192) void newtoken_kernel(
    const float* __restrict__ outv, const float* __restrict__ Wo,
    const float* __restrict__ bo, float* __restrict__ out0) {
  __shared__ float4 ov4[64];
  const int b = blockIdx.x, q = blockIdx.y, t = threadIdx.x;
  const int wave = t >> 6, lane = t & 63;
  if (t < 64) ov4[t] = ((const float4*)(outv + b * U_))[t];
  __syncthreads();
  const int dbase = q * 192 + wave * 64;
  const float4 o = ov4[lane];
  for (int i = 0; i < 64; ++i) {
    const int d = dbase + i;
    const float4 w = ((const float4*)(Wo + (size_t)d * U_))[lane];
    float acc = w.x * o.x + w.y * o.y + w.z * o.z + w.w * o.w;
    #pragma unroll
    for (int off = 32; off > 0; off >>= 1) acc += __shfl_down(acc, off, 64);
    if (lane == 0)
      out0[((size_t)b * OUTROWS_ + (OUTROWS_ - 1)) * D_ + d] = bo[d] + acc;
  }
}

extern "C" void kernel_launch(void* const* d_in, const int* in_sizes, int n_in,
                              void* d_out, int out_size, void* d_ws, size_t ws_size,
                              hipStream_t stream) {
  const float* hidden = (const float*)d_in[0];
  const float* mask   = (const float*)d_in[1];
  const float* sas    = (const float*)d_in[2];
  const float* Wq     = (const float*)d_in[3];
  const float* Wk     = (const float*)d_in[4];
  const float* Wv     = (const float*)d_in[5];
  const float* Wo     = (const float*)d_in[6];
  const float* bo     = (const float*)d_in[7];

  float* out0 = (float*)d_out;                       // (B,130,D)
  float* out1 = out0 + (size_t)B_ * OUTROWS_ * D_;   // (B,1,1,130)

  // Workspace (floats) — every buffer fully overwritten before read each run.
  float* part      = (float*)d_ws;                            // B*64*L
  float* sent_part = part + (size_t)B_ * IMPCH_ * L_;         // B*16*D
  float* wqe       = sent_part + (size_t)B_ * 16 * D_;        // B*NH*D
  float* scores    = wqe + (size_t)B_ * NH_ * D_;             // B*NH*L
  float* outv      = scores + (size_t)B_ * NH_ * L_;          // B*U

  front_kernel<<<B_ * IMPCH_ + B_ * 16, 768, 0, stream>>>(sas, hidden, mask,
                                                          part, sent_part);
  qproj_topk_kernel<<<80, 768, 0, stream>>>(sent_part, Wq, Wk, wqe,
                                            part, mask, hidden, out0, out1, outv);
  score_kernel<<<dim3(B_, 16), 256, 0, stream>>>(hidden, mask, wqe, scores);
  ctx_outv_kernel<<<dim3(B_, 16), 768, 0, stream>>>(hidden, scores, Wv, outv);
  newtoken_kernel<<<dim3(B_, 4), 192, 0, stream>>>(outv, Wo, bo, out0);
}